// Round 1
// baseline (3289.575 us; speedup 1.0000x reference)
//
#include <hip/hip_runtime.h>
#include <math.h>

// Problem constants
#define BB   32
#define TT   512
#define DIM  512
#define HID  1024
#define QQ   8
#define CC   256
#define DD   256
#define BT   16384            // BB*TT
#define EPSB 1e-5f

// ---------------------------------------------------------------------------
// Transpose x (B, DIM, T) -> xt (B*T, DIM)
// ---------------------------------------------------------------------------
__global__ __launch_bounds__(256) void transpose_xt(const float* __restrict__ x,
                                                    float* __restrict__ xt) {
  __shared__ float tile[32][33];
  int tx = threadIdx.x;        // 0..31
  int ty = threadIdx.y;        // 0..7
  int b  = blockIdx.z;
  int t0 = blockIdx.x * 32;
  int c0 = blockIdx.y * 32;
  const float* xb = x + (size_t)b * DIM * TT;
#pragma unroll
  for (int j = 0; j < 32; j += 8)
    tile[ty + j][tx] = xb[(size_t)(c0 + ty + j) * TT + (t0 + tx)];
  __syncthreads();
  float* xtb = xt + ((size_t)b * TT) * DIM;
#pragma unroll
  for (int j = 0; j < 32; j += 8)
    xtb[(size_t)(t0 + ty + j) * DIM + (c0 + tx)] = tile[tx][ty + j];
}

// ---------------------------------------------------------------------------
// fp32 NT GEMM: C[m,n] = sum_k A[m*lda+k] * W[n*ldw+k] + bias[n]
// BM=BN=128, BK=8, 256 threads, 8x8 per thread. All dims divide evenly.
// ---------------------------------------------------------------------------
__global__ __launch_bounds__(256) void sgemm_nt(const float* __restrict__ A, int lda,
                                                const float* __restrict__ W, int ldw,
                                                const float* __restrict__ bias,
                                                float* __restrict__ C, int ldc, int K) {
  __shared__ float As[8][128];
  __shared__ float Ws[8][128];
  const int tid = threadIdx.x;
  const int m0 = blockIdx.y * 128;
  const int n0 = blockIdx.x * 128;
  const int lr = tid >> 1;           // 0..127
  const int lk = (tid & 1) << 2;     // 0 or 4
  const float* Ap = A + (size_t)(m0 + lr) * lda + lk;
  const float* Wp = W + (size_t)(n0 + lr) * ldw + lk;
  const int tm = (tid >> 4) << 3;
  const int tn = (tid & 15) << 3;

  float acc[8][8];
#pragma unroll
  for (int i = 0; i < 8; i++)
#pragma unroll
    for (int j = 0; j < 8; j++) acc[i][j] = 0.f;

  for (int kb = 0; kb < K; kb += 8) {
    float4 av = *(const float4*)(Ap + kb);
    float4 wv = *(const float4*)(Wp + kb);
    __syncthreads();
    As[lk + 0][lr] = av.x; As[lk + 1][lr] = av.y;
    As[lk + 2][lr] = av.z; As[lk + 3][lr] = av.w;
    Ws[lk + 0][lr] = wv.x; Ws[lk + 1][lr] = wv.y;
    Ws[lk + 2][lr] = wv.z; Ws[lk + 3][lr] = wv.w;
    __syncthreads();
#pragma unroll
    for (int k = 0; k < 8; ++k) {
      float a[8], b[8];
      *(float4*)(a)     = *(const float4*)(&As[k][tm]);
      *(float4*)(a + 4) = *(const float4*)(&As[k][tm + 4]);
      *(float4*)(b)     = *(const float4*)(&Ws[k][tn]);
      *(float4*)(b + 4) = *(const float4*)(&Ws[k][tn + 4]);
#pragma unroll
      for (int i = 0; i < 8; i++)
#pragma unroll
        for (int j = 0; j < 8; j++) acc[i][j] = fmaf(a[i], b[j], acc[i][j]);
    }
  }

  float bv[8];
#pragma unroll
  for (int j = 0; j < 8; j++) bv[j] = bias ? bias[n0 + tn + j] : 0.f;
#pragma unroll
  for (int i = 0; i < 8; i++) {
    float* Cp = C + (size_t)(m0 + tm + i) * ldc + (n0 + tn);
    float4 o;
    o.x = acc[i][0] + bv[0]; o.y = acc[i][1] + bv[1];
    o.z = acc[i][2] + bv[2]; o.w = acc[i][3] + bv[3];
    *(float4*)Cp = o;
    o.x = acc[i][4] + bv[4]; o.y = acc[i][5] + bv[5];
    o.z = acc[i][6] + bv[6]; o.w = acc[i][7] + bv[7];
    *(float4*)(Cp + 4) = o;
  }
}

// ---------------------------------------------------------------------------
// BatchNorm (training-mode): column sums / sumsq over M=16384 rows
// ---------------------------------------------------------------------------
__global__ __launch_bounds__(256) void colstats(const float* __restrict__ h, int N,
                                                float* __restrict__ sums) {
  int col = blockIdx.x * 256 + threadIdx.x;
  size_t base = (size_t)blockIdx.y * 256 * N + col;
  float s = 0.f, s2 = 0.f;
  for (int r = 0; r < 256; r++) {
    float v = h[base + (size_t)r * N];
    s += v;
    s2 = fmaf(v, v, s2);
  }
  atomicAdd(&sums[col], s);
  atomicAdd(&sums[N + col], s2);
}

__global__ __launch_bounds__(256) void bn_finalize(const float* __restrict__ sums,
                                                   const float* __restrict__ gamma,
                                                   const float* __restrict__ beta,
                                                   float* __restrict__ ss, int N) {
  int n = blockIdx.x * 256 + threadIdx.x;
  if (n >= N) return;
  const float invM = 1.0f / (float)BT;
  float mean = sums[n] * invM;
  float var = sums[N + n] * invM - mean * mean;
  float sc = gamma[n] / sqrtf(var + EPSB);
  ss[n] = sc;
  ss[N + n] = beta[n] - mean * sc;
}

__global__ __launch_bounds__(256) void bn_apply(float* __restrict__ h,
                                                const float* __restrict__ ss,
                                                int nmask, int N, long n4, int relu) {
  long stride = (long)gridDim.x * 256;
  for (long i = (long)blockIdx.x * 256 + threadIdx.x; i < n4; i += stride) {
    int col = (int)((i << 2) & nmask);
    float4 v = ((float4*)h)[i];
    float4 sc = *(const float4*)(ss + col);
    float4 sh = *(const float4*)(ss + N + col);
    v.x = fmaf(v.x, sc.x, sh.x);
    v.y = fmaf(v.y, sc.y, sh.y);
    v.z = fmaf(v.z, sc.z, sh.z);
    v.w = fmaf(v.w, sc.w, sh.w);
    if (relu) {
      v.x = fmaxf(v.x, 0.f); v.y = fmaxf(v.y, 0.f);
      v.z = fmaxf(v.z, 0.f); v.w = fmaxf(v.w, 0.f);
    }
    ((float4*)h)[i] = v;
  }
}

// ---------------------------------------------------------------------------
// Per-(bt,q) argmax of raw logits (-> indices output, float) and of
// gumbel-perturbed temp-scaled logits (-> code index for decoder).
// One wave per row of 256 logits. logq holds logits for this q: (BT, 256).
// ---------------------------------------------------------------------------
__global__ __launch_bounds__(256) void argmax_gumbel(const float* __restrict__ logq,
                                                     const float* __restrict__ u,
                                                     const float* __restrict__ log_temps,
                                                     int q,
                                                     float* __restrict__ out_idx,
                                                     int* __restrict__ idx2) {
  int tid = threadIdx.x;
  int lane = tid & 63;
  int w = tid >> 6;
  int bt = blockIdx.x * 4 + w;
  const float* row = logq + (size_t)bt * CC;
  float4 lv = *(const float4*)(row + lane * 4);
  const float* urow = u + ((size_t)bt * QQ + q) * CC;
  float4 uv = *(const float4*)(urow + lane * 4);
  float scale = expf(-log_temps[q]);

  float l[4] = {lv.x, lv.y, lv.z, lv.w};
  float uu[4] = {uv.x, uv.y, uv.z, uv.w};
  float bvv = -INFINITY; int bi = 0;
  float gv = -INFINITY; int gi = 0;
#pragma unroll
  for (int j = 0; j < 4; j++) {
    int c = lane * 4 + j;
    if (l[j] > bvv) { bvv = l[j]; bi = c; }
    float uc = fminf(fmaxf(uu[j], 1e-9f), 1.0f);
    float g = -logf(-logf(uc) + 1e-20f);
    float y = l[j] * scale + g;
    if (y > gv) { gv = y; gi = c; }
  }
#pragma unroll
  for (int off = 32; off > 0; off >>= 1) {
    float bv2 = __shfl_down(bvv, off); int bi2 = __shfl_down(bi, off);
    if (bv2 > bvv || (bv2 == bvv && bi2 < bi)) { bvv = bv2; bi = bi2; }
    float gv2 = __shfl_down(gv, off); int gi2 = __shfl_down(gi, off);
    if (gv2 > gv || (gv2 == gv && gi2 < gi)) { gv = gv2; gi = gi2; }
  }
  if (lane == 0) {
    out_idx[(size_t)bt * QQ + q] = (float)bi;
    idx2[(size_t)bt * QQ + q] = gi;
  }
}

// ---------------------------------------------------------------------------
// emb[bt, d] = sum_q codebook[q, idx2[bt,q], d]   (one-hot codes @ codebook)
// ---------------------------------------------------------------------------
__global__ __launch_bounds__(256) void emb_gather(const float* __restrict__ cb,
                                                  const int* __restrict__ idx2,
                                                  float* __restrict__ emb) {
  __shared__ int k[QQ];
  int bt = blockIdx.x;
  int d = threadIdx.x;
  if (d < QQ) k[d] = idx2[bt * QQ + d];
  __syncthreads();
  float s = 0.f;
#pragma unroll
  for (int q = 0; q < QQ; q++) s += cb[((size_t)(q * CC + k[q])) * DD + d];
  emb[(size_t)bt * DD + d] = s;
}

// ---------------------------------------------------------------------------
// commit loss: mean((x_reco - xt)^2) over 8.4M elements
// ---------------------------------------------------------------------------
__global__ __launch_bounds__(256) void loss_kernel(const float* __restrict__ xr,
                                                   const float* __restrict__ xt,
                                                   float* __restrict__ out) {
  const long n4 = (long)BT * DIM / 4;
  float s = 0.f;
  long stride = (long)gridDim.x * 256;
  for (long i = (long)blockIdx.x * 256 + threadIdx.x; i < n4; i += stride) {
    float4 a = ((const float4*)xr)[i];
    float4 b = ((const float4*)xt)[i];
    float dx = a.x - b.x, dy = a.y - b.y, dz = a.z - b.z, dw = a.w - b.w;
    s = fmaf(dx, dx, s); s = fmaf(dy, dy, s);
    s = fmaf(dz, dz, s); s = fmaf(dw, dw, s);
  }
#pragma unroll
  for (int off = 32; off > 0; off >>= 1) s += __shfl_down(s, off);
  __shared__ float red[4];
  if ((threadIdx.x & 63) == 0) red[threadIdx.x >> 6] = s;
  __syncthreads();
  if (threadIdx.x == 0)
    atomicAdd(out, (red[0] + red[1] + red[2] + red[3]) * (1.0f / (float)(BT * DIM)));
}

// ---------------------------------------------------------------------------
// Workspace layout (in floats)
// ---------------------------------------------------------------------------
static const size_t OF_XT = 0;                         //  8,388,608 (xt)
static const size_t OF_R1 = OF_XT + (size_t)BT * DIM;  // 16,777,216 (h0 / emb)
static const size_t OF_R2 = OF_R1 + (size_t)BT * 1024; // 16,777,216 (h1 / dec_h1)
static const size_t OF_R3 = OF_R2 + (size_t)BT * 1024; // 16,777,216 (zq+logq / dec_h0)
static const size_t OF_I2 = OF_R3 + (size_t)BT * 1024; // idx2 ints (131072)
static const size_t OF_ST = OF_I2 + (size_t)BT * QQ;   // stats 4096
static const size_t OF_SS = OF_ST + 4096;              // scale/shift 4096

extern "C" void kernel_launch(void* const* d_in, const int* in_sizes, int n_in,
                              void* d_out, int out_size, void* d_ws, size_t ws_size,
                              hipStream_t stream) {
  const float* x        = (const float*)d_in[0];
  const float* u        = (const float*)d_in[1];
  const float* codebook = (const float*)d_in[2];
  const float* log_temps= (const float*)d_in[3];
  const float* enc_w0   = (const float*)d_in[4];
  const float* enc_b0   = (const float*)d_in[5];
  const float* enc_g0   = (const float*)d_in[6];
  const float* enc_be0  = (const float*)d_in[7];
  const float* enc_w1   = (const float*)d_in[8];
  const float* enc_b1   = (const float*)d_in[9];
  const float* enc_g1   = (const float*)d_in[10];
  const float* enc_be1  = (const float*)d_in[11];
  const float* enc_wo   = (const float*)d_in[12];
  const float* enc_bo   = (const float*)d_in[13];
  const float* dec_g    = (const float*)d_in[14];
  const float* dec_be   = (const float*)d_in[15];
  const float* dec_w0   = (const float*)d_in[16];
  const float* dec_b0   = (const float*)d_in[17];
  const float* dec_g0   = (const float*)d_in[18];
  const float* dec_be0  = (const float*)d_in[19];
  const float* dec_w1   = (const float*)d_in[20];
  const float* dec_b1   = (const float*)d_in[21];
  const float* dec_g1   = (const float*)d_in[22];
  const float* dec_be1  = (const float*)d_in[23];
  const float* fin_w    = (const float*)d_in[24];
  const float* fin_b    = (const float*)d_in[25];

  float* ws   = (float*)d_ws;
  float* xt   = ws + OF_XT;
  float* R1   = ws + OF_R1;
  float* R2   = ws + OF_R2;
  float* R3   = ws + OF_R3;
  float* zq   = R3;                        // (BT, 256)
  float* logq = R3 + (size_t)BT * DD;      // (BT, 256)
  int*   idx2 = (int*)(ws + OF_I2);
  float* stats= ws + OF_ST;
  float* ssb  = ws + OF_SS;

  float* out      = (float*)d_out;
  float* out_idx  = out + (size_t)BT * DIM;            // 131072 floats
  float* out_loss = out + (size_t)BT * DIM + BT * QQ;  // 1 float

  // zero the loss accumulator (d_out is poisoned before every timed launch)
  hipMemsetAsync(out_loss, 0, sizeof(float), stream);

  // BN helper: stats -> finalize -> apply (in place)
  auto bn = [&](float* h, int N, const float* g, const float* be, int relu) {
    hipMemsetAsync(stats, 0, (size_t)2 * N * sizeof(float), stream);
    colstats<<<dim3(N / 256, 64), 256, 0, stream>>>(h, N, stats);
    bn_finalize<<<dim3((N + 255) / 256), 256, 0, stream>>>(stats, g, be, ssb, N);
    long n4 = (long)BT * N / 4;
    bn_apply<<<dim3(2048), 256, 0, stream>>>(h, ssb, N - 1, N, n4, relu);
  };

  // 1. xt = transpose(x)
  transpose_xt<<<dim3(TT / 32, DIM / 32, BB), dim3(32, 8), 0, stream>>>(x, xt);

  // 2. encoder layer 0: h0 = relu(bn(xt @ enc_w0^T + b0))
  sgemm_nt<<<dim3(HID / 128, BT / 128), 256, 0, stream>>>(xt, DIM, enc_w0, DIM,
                                                          enc_b0, R1, HID, DIM);
  bn(R1, HID, enc_g0, enc_be0, 1);

  // 3. encoder layer 1: h1 = relu(bn(h0 @ enc_w1^T + b1))
  sgemm_nt<<<dim3(HID / 128, BT / 128), 256, 0, stream>>>(R1, HID, enc_w1, HID,
                                                          enc_b1, R2, HID, HID);
  bn(R2, HID, enc_g1, enc_be1, 1);

  // 4. per codebook q: z_q = h1 @ enc_wo_q^T + bo_q ; logits_q = z_q @ cb_q^T ;
  //    argmax (raw -> indices, gumbel -> code idx)
  for (int q = 0; q < QQ; q++) {
    sgemm_nt<<<dim3(DD / 128, BT / 128), 256, 0, stream>>>(
        R2, HID, enc_wo + (size_t)q * DD * HID, HID, enc_bo + q * DD, zq, DD, HID);
    sgemm_nt<<<dim3(CC / 128, BT / 128), 256, 0, stream>>>(
        zq, DD, codebook + (size_t)q * CC * DD, DD, nullptr, logq, CC, DD);
    argmax_gumbel<<<dim3(BT / 4), 256, 0, stream>>>(logq, u, log_temps, q,
                                                    out_idx, idx2);
  }

  // 5. emb = one_hot(codes) @ codebook  (gather-sum), then bn (no relu)
  emb_gather<<<dim3(BT), 256, 0, stream>>>(codebook, idx2, R1);
  bn(R1, DD, dec_g, dec_be, 0);

  // 6. decoder FFN
  sgemm_nt<<<dim3(HID / 128, BT / 128), 256, 0, stream>>>(R1, DD, dec_w0, DD,
                                                          dec_b0, R3, HID, DD);
  bn(R3, HID, dec_g0, dec_be0, 1);
  sgemm_nt<<<dim3(HID / 128, BT / 128), 256, 0, stream>>>(R3, HID, dec_w1, HID,
                                                          dec_b1, R2, HID, HID);
  bn(R2, HID, dec_g1, dec_be1, 1);

  // 7. x_reco = h @ fin_w^T + fin_b  -> directly into d_out
  sgemm_nt<<<dim3(DIM / 128, BT / 128), 256, 0, stream>>>(R2, HID, fin_w, HID,
                                                          fin_b, out, DIM, HID);

  // 8. commit loss
  loss_kernel<<<dim3(2048), 256, 0, stream>>>(out, xt, out_loss);
}